// Round 1
// 7353.014 us; speedup vs baseline: 3.3990x; 3.3990x over previous
//
#include <hip/hip_runtime.h>
#include <math.h>

#define D 512
#define TSEQ 2048
#define NH 8
#define HD 64
#define NTOK 4096   // B*T
#define VOCAB 32000
#define NLAYER 6

__device__ __forceinline__ float wave_sum(float x) {
#pragma unroll
  for (int off = 32; off; off >>= 1) x += __shfl_xor(x, off, 64);
  return x;
}
__device__ __forceinline__ float wave_max(float x) {
#pragma unroll
  for (int off = 32; off; off >>= 1) x = fmaxf(x, __shfl_xor(x, off, 64));
  return x;
}
// uniform-lane broadcast via SALU readlane (co-issues with VALU fma stream)
__device__ __forceinline__ float bcast(float x, int l) {
  return __uint_as_float(__builtin_amdgcn_readlane(__float_as_uint(x), l));
}

// x[n,d] = tok_emb[idx[n],d] + pos_emb[n % T, d]   (float4 granularity)
__global__ __launch_bounds__(256) void embed_kernel(
    const int* __restrict__ idx, const float* __restrict__ tok,
    const float* __restrict__ pos, float* __restrict__ x) {
  int i = blockIdx.x * 256 + threadIdx.x;      // float4 index, NTOK*D/4 total
  int n = i >> 7;                              // 128 float4 per row
  int c4 = (i & 127) << 2;
  int t = n & (TSEQ - 1);
  int tk = idx[n];
  float4 a = *(const float4*)(tok + (size_t)tk * D + c4);
  float4 p = *(const float4*)(pos + (size_t)t * D + c4);
  float4 r;
  r.x = a.x + p.x; r.y = a.y + p.y; r.z = a.z + p.z; r.w = a.w + p.w;
  *(float4*)(x + (size_t)n * D + c4) = r;
}

// one wave per row, D=512 -> 8 elems/lane; two-pass mean/var (matches ref)
__global__ __launch_bounds__(256) void ln_kernel(
    const float* __restrict__ x, const float* __restrict__ g,
    const float* __restrict__ b, float* __restrict__ out) {
  int lane = threadIdx.x & 63;
  int row = blockIdx.x * 4 + (threadIdx.x >> 6);
  const float* xr = x + (size_t)row * D;
  float vals[8];
  float s = 0.f;
#pragma unroll
  for (int i = 0; i < 8; ++i) { vals[i] = xr[lane + 64 * i]; s += vals[i]; }
  s = wave_sum(s);
  float mean = s * (1.f / D);
  float vs = 0.f;
#pragma unroll
  for (int i = 0; i < 8; ++i) { float d = vals[i] - mean; vs += d * d; }
  vs = wave_sum(vs);
  float rstd = 1.f / sqrtf(vs * (1.f / D) + 1e-5f);
  float* orow = out + (size_t)row * D;
#pragma unroll
  for (int i = 0; i < 8; ++i) {
    int c = lane + 64 * i;
    orow[c] = (vals[i] - mean) * rstd * g[c] + b[c];
  }
}

// C[M,N] = act(A[M,K] @ B[K,N] + bias + R); 64x64 tile, 16 k-step, 4x4 micro
template <bool RELU, bool BIAS, bool RES>
__global__ __launch_bounds__(256) void gemm_kernel(
    const float* __restrict__ A, const float* __restrict__ Bm,
    const float* __restrict__ bias, const float* __restrict__ R,
    float* __restrict__ C, int M, int N, int K) {
  __shared__ float As[16][72];   // [k][m], padded
  __shared__ float Bs[16][64];   // [k][n]
  const int tid = threadIdx.x;
  const int tx = tid & 15, ty = tid >> 4;
  const int m0 = blockIdx.y * 64, n0 = blockIdx.x * 64;
  const int lar = tid >> 2, lak = (tid & 3) << 2;
  const int lbk = tid >> 4, lbn = (tid & 15) << 2;
  const float* Aptr = A + (size_t)(m0 + lar) * K + lak;
  const float* Bptr = Bm + (size_t)lbk * N + n0 + lbn;
  float acc[4][4] = {};
  for (int k0 = 0; k0 < K; k0 += 16) {
    float4 av = *(const float4*)(Aptr + k0);
    float4 bv = *(const float4*)(Bptr + (size_t)k0 * N);
    __syncthreads();
    As[lak + 0][lar] = av.x; As[lak + 1][lar] = av.y;
    As[lak + 2][lar] = av.z; As[lak + 3][lar] = av.w;
    *(float4*)&Bs[lbk][lbn] = bv;
    __syncthreads();
#pragma unroll
    for (int kk = 0; kk < 16; ++kk) {
      float af[4], bf[4];
      *(float4*)af = *(const float4*)&As[kk][ty << 2];
      *(float4*)bf = *(const float4*)&Bs[kk][tx << 2];
#pragma unroll
      for (int i = 0; i < 4; ++i)
#pragma unroll
        for (int j = 0; j < 4; ++j)
          acc[i][j] = fmaf(af[i], bf[j], acc[i][j]);
    }
  }
#pragma unroll
  for (int i = 0; i < 4; ++i) {
    int m = m0 + (ty << 2) + i;
#pragma unroll
    for (int j = 0; j < 4; ++j) {
      int n = n0 + (tx << 2) + j;
      float val = acc[i][j];
      if (BIAS) val += bias[n];
      if (RES) val += R[(size_t)m * N + n];
      if (RELU) val = fmaxf(val, 0.f);
      C[(size_t)m * N + n] = val;
    }
  }
}

// Tiled flash attention.
// Block = 256 thr (4 waves) owns a 32-row query tile of one (b,h).
// Causal balance: block processes qtile `pair` then qtile `63-pair`
//   -> every block does exactly 33 K-tiles of 64 keys.
// Wave w holds 8 query rows (q,o,m,l in registers, lane = head-dim).
// QK^T: lane = key j; s_j[r] += readlane(q[r], d) * Ks[j][d]  (Ks padded 65
//   -> (j+d)%32 banks, 2-way = free). One wave_max+wave_sum per ROW per tile.
// PV:   lane = dim d; o[r] += readlane(p[r], j) * Vs[j][d]  (broadcast row,
//   conflict-free).
__global__ __launch_bounds__(256) void attn_kernel(
    const float* __restrict__ qg, const float* __restrict__ kg,
    const float* __restrict__ vg, float* __restrict__ og) {
  __shared__ float Ks[64][65];
  __shared__ float Vs[64][64];
  const int tid = threadIdx.x;
  const int lane = tid & 63;
  const int w = tid >> 6;
  const int pair = blockIdx.x & 31;          // 32 qtile-pairs per (b,h)
  const int bh = blockIdx.x >> 5;
  const int h = bh & (NH - 1);
  const int b = bh >> 3;
  const size_t base = (size_t)b * TSEQ * D + (size_t)h * HD;
  const float scale = 0.04419417382415922f;  // 512^-0.5 (ref scales by D)
  const int sr = tid >> 4;                   // staging row base (16 rows/iter)
  const int sc = (tid & 15) << 2;            // staging col (float4)

  for (int half = 0; half < 2; ++half) {
    const int qt = half ? (63 - pair) : pair;   // qtile index, 32 rows each
    const int q0 = qt << 5;
    const int row0 = q0 + w * 8;
    float qreg[8], oreg[8], mreg[8], lreg[8];
#pragma unroll
    for (int r = 0; r < 8; ++r) {
      qreg[r] = qg[base + (size_t)(row0 + r) * D + lane] * scale;
      oreg[r] = 0.f; mreg[r] = -INFINITY; lreg[r] = 0.f;
    }
    const int nkt = (q0 >> 6) + 1;   // K-tiles covering keys 0..q0+31
    for (int kt = 0; kt < nkt; ++kt) {
      const int j0 = kt << 6;
      __syncthreads();   // previous tile's (or half's) LDS reads done
      const float* kp = kg + base + (size_t)j0 * D;
      const float* vp = vg + base + (size_t)j0 * D;
#pragma unroll
      for (int it = 0; it < 4; ++it) {
        int jr = sr + (it << 4);
        float4 k4 = *(const float4*)(kp + (size_t)jr * D + sc);
        float4 v4 = *(const float4*)(vp + (size_t)jr * D + sc);
        Ks[jr][sc + 0] = k4.x; Ks[jr][sc + 1] = k4.y;
        Ks[jr][sc + 2] = k4.z; Ks[jr][sc + 3] = k4.w;
        *(float4*)&Vs[jr][sc] = v4;
      }
      __syncthreads();
      // ---- QK^T: lane owns key j0+lane ----
      float s[8] = {};
#pragma unroll 16
      for (int d = 0; d < 64; ++d) {
        float kd = Ks[lane][d];
#pragma unroll
        for (int r = 0; r < 8; ++r)
          s[r] = fmaf(bcast(qreg[r], d), kd, s[r]);
      }
      // causal mask (only the last K-tile can cross the diagonal)
      if (kt == nkt - 1) {
#pragma unroll
        for (int r = 0; r < 8; ++r)
          if (j0 + lane > row0 + r) s[r] = -INFINITY;
      }
      // ---- online softmax, one reduction pair per row ----
#pragma unroll
      for (int r = 0; r < 8; ++r) {
        float mb = wave_max(s[r]);
        float mn = fmaxf(mreg[r], mb);
        float p = __expf(s[r] - mn);        // masked -> exp(-inf)=0
        float ef = __expf(mreg[r] - mn);    // first tile: exp(-inf)=0
        float ps = wave_sum(p);
        lreg[r] = lreg[r] * ef + ps;
        oreg[r] *= ef;
        mreg[r] = mn;
        s[r] = p;
      }
      // ---- PV: lane owns dim, broadcast p over keys ----
#pragma unroll 16
      for (int j = 0; j < 64; ++j) {
        float vv = Vs[j][lane];
#pragma unroll
        for (int r = 0; r < 8; ++r)
          oreg[r] = fmaf(bcast(s[r], j), vv, oreg[r]);
      }
    }
#pragma unroll
    for (int r = 0; r < 8; ++r)
      og[base + (size_t)(row0 + r) * D + lane] = oreg[r] / lreg[r];
  }
}

// per-row: row_loss[r] = logsumexp(logits[r,:]) - logits[r, tg[r]]
__global__ __launch_bounds__(256) void loss_row_kernel(
    const float* __restrict__ logits, const int* __restrict__ tg,
    float* __restrict__ row_loss) {
  const int row = blockIdx.x;
  const float4* lr = (const float4*)(logits + (size_t)row * VOCAB);
  const int n4 = VOCAB / 4;  // 8000
  __shared__ float red[4];
  float mx = -INFINITY;
  for (int i = threadIdx.x; i < n4; i += 256) {
    float4 t = lr[i];
    mx = fmaxf(fmaxf(fmaxf(mx, t.x), t.y), fmaxf(t.z, t.w));
  }
  mx = wave_max(mx);
  if ((threadIdx.x & 63) == 0) red[threadIdx.x >> 6] = mx;
  __syncthreads();
  mx = fmaxf(fmaxf(red[0], red[1]), fmaxf(red[2], red[3]));
  __syncthreads();
  float se = 0.f;
  for (int i = threadIdx.x; i < n4; i += 256) {
    float4 t = lr[i];
    se += __expf(t.x - mx) + __expf(t.y - mx) + __expf(t.z - mx) + __expf(t.w - mx);
  }
  se = wave_sum(se);
  if ((threadIdx.x & 63) == 0) red[threadIdx.x >> 6] = se;
  __syncthreads();
  if (threadIdx.x == 0) {
    float tot = red[0] + red[1] + red[2] + red[3];
    const float* l = logits + (size_t)row * VOCAB;
    row_loss[row] = mx + logf(tot) - l[tg[row]];
  }
}

__global__ __launch_bounds__(256) void loss_reduce_kernel(
    const float* __restrict__ rl, float* __restrict__ out) {
  float s = 0.f;
  for (int i = threadIdx.x; i < NTOK; i += 256) s += rl[i];
  __shared__ float red[4];
  s = wave_sum(s);
  if ((threadIdx.x & 63) == 0) red[threadIdx.x >> 6] = s;
  __syncthreads();
  if (threadIdx.x == 0)
    out[0] = (red[0] + red[1] + red[2] + red[3]) * (1.f / NTOK);
}

extern "C" void kernel_launch(void* const* d_in, const int* in_sizes, int n_in,
                              void* d_out, int out_size, void* d_ws, size_t ws_size,
                              hipStream_t stream) {
  const int* idx     = (const int*)d_in[0];
  const int* targets = (const int*)d_in[1];
  const float* tok_emb = (const float*)d_in[2];
  const float* pos_emb = (const float*)d_in[3];
  const float* Wq = (const float*)d_in[4];
  const float* Wk = (const float*)d_in[5];
  const float* Wv = (const float*)d_in[6];
  const float* Wo = (const float*)d_in[7];
  const float* bo = (const float*)d_in[8];
  const float* W1 = (const float*)d_in[9];
  const float* b1 = (const float*)d_in[10];
  const float* W2 = (const float*)d_in[11];
  const float* b2 = (const float*)d_in[12];
  const float* ln1_g = (const float*)d_in[13];
  const float* ln1_b = (const float*)d_in[14];
  const float* ln2_g = (const float*)d_in[15];
  const float* ln2_b = (const float*)d_in[16];
  const float* lnf_g = (const float*)d_in[17];
  const float* lnf_b = (const float*)d_in[18];
  const float* Whead = (const float*)d_in[19];
  const float* bhead = (const float*)d_in[20];
  float* out = (float*)d_out;

  // persistent scratch in d_ws: x, h, row_loss (~16.8 MB)
  float* ws = (float*)d_ws;
  float* x = ws;
  float* h = ws + (size_t)NTOK * D;
  float* row_loss = h + (size_t)NTOK * D;

  // transient scratch aliased into d_out (dead before head GEMM writes logits)
  float* q    = out;
  float* kbuf = out + 1 * (size_t)NTOK * D;
  float* vbuf = out + 2 * (size_t)NTOK * D;
  float* obuf = out + 3 * (size_t)NTOK * D;
  float* mlp  = out + 4 * (size_t)NTOK * D;  // NTOK*4D floats

  embed_kernel<<<NTOK * D / 4 / 256, 256, 0, stream>>>(idx, tok_emb, pos_emb, x);

  const dim3 g512(D / 64, NTOK / 64);
  const dim3 g2048(4 * D / 64, NTOK / 64);
  const int attn_grid = (NTOK / TSEQ) * NH * (TSEQ / 64);  // B*H*32 = 512
  for (int l = 0; l < NLAYER; ++l) {
    ln_kernel<<<NTOK / 4, 256, 0, stream>>>(x, ln1_g + l * D, ln1_b + l * D, h);
    gemm_kernel<false, false, false><<<g512, 256, 0, stream>>>(
        h, Wq + (size_t)l * D * D, nullptr, nullptr, q, NTOK, D, D);
    gemm_kernel<false, false, false><<<g512, 256, 0, stream>>>(
        h, Wk + (size_t)l * D * D, nullptr, nullptr, kbuf, NTOK, D, D);
    gemm_kernel<false, false, false><<<g512, 256, 0, stream>>>(
        h, Wv + (size_t)l * D * D, nullptr, nullptr, vbuf, NTOK, D, D);
    attn_kernel<<<attn_grid, 256, 0, stream>>>(q, kbuf, vbuf, obuf);
    gemm_kernel<false, true, true><<<g512, 256, 0, stream>>>(
        obuf, Wo + (size_t)l * D * D, bo + l * D, x, x, NTOK, D, D);
    ln_kernel<<<NTOK / 4, 256, 0, stream>>>(x, ln2_g + l * D, ln2_b + l * D, h);
    gemm_kernel<true, true, false><<<g2048, 256, 0, stream>>>(
        h, W1 + (size_t)l * D * 4 * D, b1 + l * 4 * D, nullptr, mlp, NTOK, 4 * D, D);
    gemm_kernel<false, true, true><<<g512, 256, 0, stream>>>(
        mlp, W2 + (size_t)l * 4 * D * D, b2 + l * D, x, x, NTOK, D, 4 * D);
  }
  ln_kernel<<<NTOK / 4, 256, 0, stream>>>(x, lnf_g, lnf_b, h);
  const dim3 ghead(VOCAB / 64, NTOK / 64);
  gemm_kernel<false, true, false><<<ghead, 256, 0, stream>>>(
      h, Whead, bhead, nullptr, out, NTOK, VOCAB, D);
  loss_row_kernel<<<NTOK, 256, 0, stream>>>(out, targets, row_loss);
  loss_reduce_kernel<<<1, 256, 0, stream>>>(row_loss, out + (size_t)NTOK * VOCAB);
}

// Round 2
// 4388.883 us; speedup vs baseline: 5.6946x; 1.6754x over previous
//
#include <hip/hip_runtime.h>
#include <math.h>

#define D 512
#define TSEQ 2048
#define NH 8
#define HD 64
#define NTOK 4096   // B*T
#define VOCAB 32000
#define NLAYER 6

typedef __attribute__((ext_vector_type(8))) short short8;   // 8 bf16 = 4 VGPR
typedef __attribute__((ext_vector_type(4))) float f32x4;

__device__ __forceinline__ float wave_sum(float x) {
#pragma unroll
  for (int off = 32; off; off >>= 1) x += __shfl_xor(x, off, 64);
  return x;
}
__device__ __forceinline__ float wave_max(float x) {
#pragma unroll
  for (int off = 32; off; off >>= 1) x = fmaxf(x, __shfl_xor(x, off, 64));
  return x;
}
// uniform-lane broadcast via SALU readlane (co-issues with VALU fma stream)
__device__ __forceinline__ float bcast(float x, int l) {
  return __uint_as_float(__builtin_amdgcn_readlane(__float_as_uint(x), l));
}
// fp32 -> bf16 round-to-nearest-even
__device__ __forceinline__ unsigned short f2bf(float f) {
  unsigned int u = __float_as_uint(f);
  u += 0x7fffu + ((u >> 16) & 1u);
  return (unsigned short)(u >> 16);
}
// async global->LDS, 16B per lane; lds base must be wave-uniform
__device__ __forceinline__ void gload_lds16(const unsigned short* g, void* lds) {
  __builtin_amdgcn_global_load_lds(
      (const __attribute__((address_space(1))) void*)g,
      (__attribute__((address_space(3))) void*)lds, 16, 0, 0);
}

// x[n,d] = tok_emb[idx[n],d] + pos_emb[n % T, d]   (float4 granularity)
__global__ __launch_bounds__(256) void embed_kernel(
    const int* __restrict__ idx, const float* __restrict__ tok,
    const float* __restrict__ pos, float* __restrict__ x) {
  int i = blockIdx.x * 256 + threadIdx.x;      // float4 index, NTOK*D/4 total
  int n = i >> 7;                              // 128 float4 per row
  int c4 = (i & 127) << 2;
  int t = n & (TSEQ - 1);
  int tk = idx[n];
  float4 a = *(const float4*)(tok + (size_t)tk * D + c4);
  float4 p = *(const float4*)(pos + (size_t)t * D + c4);
  float4 r;
  r.x = a.x + p.x; r.y = a.y + p.y; r.z = a.z + p.z; r.w = a.w + p.w;
  *(float4*)(x + (size_t)n * D + c4) = r;
}

// one wave per row, D=512 -> 8 elems/lane; two-pass mean/var (matches ref)
// output bf16 (consumed only by GEMM A-operands)
__global__ __launch_bounds__(256) void ln_kernel(
    const float* __restrict__ x, const float* __restrict__ g,
    const float* __restrict__ b, unsigned short* __restrict__ out) {
  int lane = threadIdx.x & 63;
  int row = blockIdx.x * 4 + (threadIdx.x >> 6);
  const float* xr = x + (size_t)row * D;
  float vals[8];
  float s = 0.f;
#pragma unroll
  for (int i = 0; i < 8; ++i) { vals[i] = xr[lane + 64 * i]; s += vals[i]; }
  s = wave_sum(s);
  float mean = s * (1.f / D);
  float vs = 0.f;
#pragma unroll
  for (int i = 0; i < 8; ++i) { float d = vals[i] - mean; vs += d * d; }
  vs = wave_sum(vs);
  float rstd = 1.f / sqrtf(vs * (1.f / D) + 1e-5f);
  unsigned short* orow = out + (size_t)row * D;
#pragma unroll
  for (int i = 0; i < 8; ++i) {
    int c = lane + 64 * i;
    orow[c] = f2bf((vals[i] - mean) * rstd * g[c] + b[c]);
  }
}

// W [K][N] fp32 (+z*K*Nsrc) -> WT [NT][K] bf16 (+z*NT*K); cols [n0, n0+NT)
__global__ __launch_bounds__(256) void transpose_cvt(
    const float* __restrict__ src, unsigned short* __restrict__ dst,
    int K, int Nsrc, int n0, int NT) {
  src += (size_t)blockIdx.z * K * Nsrc;
  dst += (size_t)blockIdx.z * NT * K;
  const int kt = blockIdx.y << 5, nt = blockIdx.x << 5;
  __shared__ float t[32][33];
  const int tid = threadIdx.x;
  const int r = tid >> 3, c4 = (tid & 7) << 2;
  float4 v = *(const float4*)(src + (size_t)(kt + r) * Nsrc + n0 + nt + c4);
  t[r][c4 + 0] = v.x; t[r][c4 + 1] = v.y;
  t[r][c4 + 2] = v.z; t[r][c4 + 3] = v.w;
  __syncthreads();
  ushort4 o;
  o.x = f2bf(t[c4 + 0][r]); o.y = f2bf(t[c4 + 1][r]);
  o.z = f2bf(t[c4 + 2][r]); o.w = f2bf(t[c4 + 3][r]);
  *(ushort4*)(dst + (size_t)(nt + r) * K + kt + c4) = o;
}

// C[M,N] = act(A[M,K]bf16 @ BT[N,K]bf16^T + bias + R)
// 128x128 tile, BK=32, 4 waves (2x2), mfma_f32_16x16x32_bf16.
// LDS linear [128][32] bf16 per operand, staged via global_load_lds(16B);
// chunk XOR swizzle (kg ^ ((row>>1)&3)) applied on the GLOBAL source and on
// the ds_read side -> 2-way (free) fragment reads.
template <bool RELU, bool BIAS, bool RES, bool OUTBF>
__global__ __launch_bounds__(256) void gemm_bf16_kernel(
    const unsigned short* __restrict__ A, const unsigned short* __restrict__ BT,
    const float* __restrict__ bias, const float* __restrict__ R,
    void* __restrict__ Cv, int M, int N, int K, int ldc) {
  __shared__ unsigned short As[128 * 32];
  __shared__ unsigned short Bs[128 * 32];
  const int tid = threadIdx.x;
  const int lane = tid & 63;
  const int w = tid >> 6;
  const int m0 = blockIdx.y * 128, n0 = blockIdx.x * 128;
  // staging: 512 16B-chunks per operand tile; thread t stages chunks t, t+256
  const int c0 = tid, c1 = tid + 256;
  const int r0 = c0 >> 2, k0c = (c0 & 3) ^ ((r0 >> 1) & 3);
  const int r1 = c1 >> 2, k1c = (c1 & 3) ^ ((r1 >> 1) & 3);
  const unsigned short* Ag0 = A + (size_t)(m0 + r0) * K + k0c * 8;
  const unsigned short* Ag1 = A + (size_t)(m0 + r1) * K + k1c * 8;
  const unsigned short* Bg0 = BT + (size_t)(n0 + r0) * K + k0c * 8;
  const unsigned short* Bg1 = BT + (size_t)(n0 + r1) * K + k1c * 8;
  char* AsLo = (char*)As + w * 1024;        // wave-uniform LDS bases
  char* AsHi = AsLo + 4096;
  char* BsLo = (char*)Bs + w * 1024;
  char* BsHi = BsLo + 4096;
  // fragment addressing
  const int wr = w >> 1, wc = w & 1;
  const int fr = lane & 15, kg = lane >> 4;
  const int swz = (fr >> 1) & 3;
  const int fcol = ((kg ^ swz) << 4);
  const char* Ard = (const char*)As + wr * 4096 + fr * 64 + fcol;
  const char* Brd = (const char*)Bs + wc * 4096 + fr * 64 + fcol;
  f32x4 acc[4][4] = {};
  for (int kk = 0; kk < K; kk += 32) {
    __syncthreads();                       // prior frag reads done
    gload_lds16(Ag0 + kk, AsLo);
    gload_lds16(Ag1 + kk, AsHi);
    gload_lds16(Bg0 + kk, BsLo);
    gload_lds16(Bg1 + kk, BsHi);
    __syncthreads();                       // compiler drains vmcnt before barrier
    short8 af[4], bf[4];
#pragma unroll
    for (int f = 0; f < 4; ++f) {
      af[f] = *(const short8*)(Ard + f * 1024);
      bf[f] = *(const short8*)(Brd + f * 1024);
    }
#pragma unroll
    for (int fi = 0; fi < 4; ++fi)
#pragma unroll
      for (int fj = 0; fj < 4; ++fj)
        acc[fi][fj] = __builtin_amdgcn_mfma_f32_16x16x32_bf16(
            af[fi], bf[fj], acc[fi][fj], 0, 0, 0);
  }
  // epilogue: D frag: col = lane&15, row = (lane>>4)*4 + reg
  float* Cf = (float*)Cv;
  unsigned short* Cb = (unsigned short*)Cv;
#pragma unroll
  for (int fi = 0; fi < 4; ++fi) {
#pragma unroll
    for (int fj = 0; fj < 4; ++fj) {
      const int n = n0 + wc * 64 + fj * 16 + fr;
      float bv = BIAS ? bias[n] : 0.f;
#pragma unroll
      for (int ri = 0; ri < 4; ++ri) {
        const int m = m0 + wr * 64 + fi * 16 + kg * 4 + ri;
        float val = acc[fi][fj][ri];
        if (BIAS) val += bv;
        if (RES) val += R[(size_t)m * ldc + n];
        if (RELU) val = fmaxf(val, 0.f);
        if (OUTBF) Cb[(size_t)m * ldc + n] = f2bf(val);
        else       Cf[(size_t)m * ldc + n] = val;
      }
    }
  }
}

// Tiled flash attention (unchanged math, bf16 output for Wo GEMM).
__global__ __launch_bounds__(256) void attn_kernel(
    const float* __restrict__ qg, const float* __restrict__ kg,
    const float* __restrict__ vg, unsigned short* __restrict__ og) {
  __shared__ float Ks[64][65];
  __shared__ float Vs[64][64];
  const int tid = threadIdx.x;
  const int lane = tid & 63;
  const int w = tid >> 6;
  const int pair = blockIdx.x & 31;          // 32 qtile-pairs per (b,h)
  const int bh = blockIdx.x >> 5;
  const int h = bh & (NH - 1);
  const int b = bh >> 3;
  const size_t base = (size_t)b * TSEQ * D + (size_t)h * HD;
  const float scale = 0.04419417382415922f;  // 512^-0.5 (ref scales by D)
  const int sr = tid >> 4;                   // staging row base (16 rows/iter)
  const int sc = (tid & 15) << 2;            // staging col (float4)

  for (int half = 0; half < 2; ++half) {
    const int qt = half ? (63 - pair) : pair;   // qtile index, 32 rows each
    const int q0 = qt << 5;
    const int row0 = q0 + w * 8;
    float qreg[8], oreg[8], mreg[8], lreg[8];
#pragma unroll
    for (int r = 0; r < 8; ++r) {
      qreg[r] = qg[base + (size_t)(row0 + r) * D + lane] * scale;
      oreg[r] = 0.f; mreg[r] = -INFINITY; lreg[r] = 0.f;
    }
    const int nkt = (q0 >> 6) + 1;   // K-tiles covering keys 0..q0+31
    for (int kt = 0; kt < nkt; ++kt) {
      const int j0 = kt << 6;
      __syncthreads();   // previous tile's (or half's) LDS reads done
      const float* kp = kg + base + (size_t)j0 * D;
      const float* vp = vg + base + (size_t)j0 * D;
#pragma unroll
      for (int it = 0; it < 4; ++it) {
        int jr = sr + (it << 4);
        float4 k4 = *(const float4*)(kp + (size_t)jr * D + sc);
        float4 v4 = *(const float4*)(vp + (size_t)jr * D + sc);
        Ks[jr][sc + 0] = k4.x; Ks[jr][sc + 1] = k4.y;
        Ks[jr][sc + 2] = k4.z; Ks[jr][sc + 3] = k4.w;
        *(float4*)&Vs[jr][sc] = v4;
      }
      __syncthreads();
      // ---- QK^T: lane owns key j0+lane ----
      float s[8] = {};
#pragma unroll 16
      for (int d = 0; d < 64; ++d) {
        float kd = Ks[lane][d];
#pragma unroll
        for (int r = 0; r < 8; ++r)
          s[r] = fmaf(bcast(qreg[r], d), kd, s[r]);
      }
      // causal mask (only the last K-tile can cross the diagonal)
      if (kt == nkt - 1) {
#pragma unroll
        for (int r = 0; r < 8; ++r)
          if (j0 + lane > row0 + r) s[r] = -INFINITY;
      }
      // ---- online softmax, one reduction pair per row ----
#pragma unroll
      for (int r = 0; r < 8; ++r) {
        float mb = wave_max(s[r]);
        float mn = fmaxf(mreg[r], mb);
        float p = __expf(s[r] - mn);        // masked -> exp(-inf)=0
        float ef = __expf(mreg[r] - mn);    // first tile: exp(-inf)=0
        float ps = wave_sum(p);
        lreg[r] = lreg[r] * ef + ps;
        oreg[r] *= ef;
        mreg[r] = mn;
        s[r] = p;
      }
      // ---- PV: lane owns dim, broadcast p over keys ----
#pragma unroll 16
      for (int j = 0; j < 64; ++j) {
        float vv = Vs[j][lane];
#pragma unroll
        for (int r = 0; r < 8; ++r)
          oreg[r] = fmaf(bcast(s[r], j), vv, oreg[r]);
      }
    }
#pragma unroll
    for (int r = 0; r < 8; ++r)
      og[base + (size_t)(row0 + r) * D + lane] = f2bf(oreg[r] / lreg[r]);
  }
}

// per-row: row_loss[r] = logsumexp(logits[r,:]) - logits[r, tg[r]]
__global__ __launch_bounds__(256) void loss_row_kernel(
    const float* __restrict__ logits, const int* __restrict__ tg,
    float* __restrict__ row_loss) {
  const int row = blockIdx.x;
  const float4* lr = (const float4*)(logits + (size_t)row * VOCAB);
  const int n4 = VOCAB / 4;  // 8000
  __shared__ float red[4];
  float mx = -INFINITY;
  for (int i = threadIdx.x; i < n4; i += 256) {
    float4 t = lr[i];
    mx = fmaxf(fmaxf(fmaxf(mx, t.x), t.y), fmaxf(t.z, t.w));
  }
  mx = wave_max(mx);
  if ((threadIdx.x & 63) == 0) red[threadIdx.x >> 6] = mx;
  __syncthreads();
  mx = fmaxf(fmaxf(red[0], red[1]), fmaxf(red[2], red[3]));
  __syncthreads();
  float se = 0.f;
  for (int i = threadIdx.x; i < n4; i += 256) {
    float4 t = lr[i];
    se += __expf(t.x - mx) + __expf(t.y - mx) + __expf(t.z - mx) + __expf(t.w - mx);
  }
  se = wave_sum(se);
  if ((threadIdx.x & 63) == 0) red[threadIdx.x >> 6] = se;
  __syncthreads();
  if (threadIdx.x == 0) {
    float tot = red[0] + red[1] + red[2] + red[3];
    const float* l = logits + (size_t)row * VOCAB;
    row_loss[row] = mx + logf(tot) - l[tg[row]];
  }
}

__global__ __launch_bounds__(256) void loss_reduce_kernel(
    const float* __restrict__ rl, float* __restrict__ out) {
  float s = 0.f;
  for (int i = threadIdx.x; i < NTOK; i += 256) s += rl[i];
  __shared__ float red[4];
  s = wave_sum(s);
  if ((threadIdx.x & 63) == 0) red[threadIdx.x >> 6] = s;
  __syncthreads();
  if (threadIdx.x == 0)
    out[0] = (red[0] + red[1] + red[2] + red[3]) * (1.f / NTOK);
}

extern "C" void kernel_launch(void* const* d_in, const int* in_sizes, int n_in,
                              void* d_out, int out_size, void* d_ws, size_t ws_size,
                              hipStream_t stream) {
  const int* idx     = (const int*)d_in[0];
  const int* targets = (const int*)d_in[1];
  const float* tok_emb = (const float*)d_in[2];
  const float* pos_emb = (const float*)d_in[3];
  const float* Wq = (const float*)d_in[4];
  const float* Wk = (const float*)d_in[5];
  const float* Wv = (const float*)d_in[6];
  const float* Wo = (const float*)d_in[7];
  const float* bo = (const float*)d_in[8];
  const float* W1 = (const float*)d_in[9];
  const float* b1 = (const float*)d_in[10];
  const float* W2 = (const float*)d_in[11];
  const float* b2 = (const float*)d_in[12];
  const float* ln1_g = (const float*)d_in[13];
  const float* ln1_b = (const float*)d_in[14];
  const float* ln2_g = (const float*)d_in[15];
  const float* ln2_b = (const float*)d_in[16];
  const float* lnf_g = (const float*)d_in[17];
  const float* lnf_b = (const float*)d_in[18];
  const float* Whead = (const float*)d_in[19];
  const float* bhead = (const float*)d_in[20];
  float* out = (float*)d_out;

  const size_t AD = (size_t)NTOK * D;          // 2,097,152 floats
  const size_t WDD = (size_t)D * D;            // 262,144
  const size_t WD4 = (size_t)D * 4 * D;        // 1,048,576

  // persistent scratch in d_ws: x(f32) + h(bf16) + row_loss + head WT chunk
  // = 8.4 + 4.2 + 0.016 + 4.2 MB = 16.8 MB (same footprint as before)
  float* x = (float*)d_ws;
  unsigned short* h = (unsigned short*)(x + AD);
  float* row_loss = (float*)(h + AD);          // h = AD ushorts = AD/2 floats
  unsigned short* WTh = (unsigned short*)(row_loss + NTOK);

  // transient scratch aliased into d_out (dead before head GEMM writes logits)
  float* q    = out;
  float* kbuf = out + AD;
  float* vbuf = out + 2 * AD;
  unsigned short* obuf = (unsigned short*)(out + 3 * AD);  // NTOK*D bf16
  unsigned short* mlp  = (unsigned short*)(out + 4 * AD);  // NTOK*4D bf16
  unsigned short* slab = (unsigned short*)(out + 6 * AD);  // bf16 W^T, 37.8 MB
  unsigned short* WqT = slab;
  unsigned short* WkT = WqT + 6 * WDD;
  unsigned short* WvT = WkT + 6 * WDD;
  unsigned short* WoT = WvT + 6 * WDD;
  unsigned short* W1T = WoT + 6 * WDD;         // [2048][512] per layer
  unsigned short* W2T = W1T + 6 * WD4;         // [512][2048] per layer

  embed_kernel<<<NTOK * D / 4 / 256, 256, 0, stream>>>(idx, tok_emb, pos_emb, x);

  // batched weight transpose+convert (all 6 layers per launch)
  transpose_cvt<<<dim3(16, 16, 6), 256, 0, stream>>>(Wq, WqT, D, D, 0, D);
  transpose_cvt<<<dim3(16, 16, 6), 256, 0, stream>>>(Wk, WkT, D, D, 0, D);
  transpose_cvt<<<dim3(16, 16, 6), 256, 0, stream>>>(Wv, WvT, D, D, 0, D);
  transpose_cvt<<<dim3(16, 16, 6), 256, 0, stream>>>(Wo, WoT, D, D, 0, D);
  transpose_cvt<<<dim3(64, 16, 6), 256, 0, stream>>>(W1, W1T, D, 4 * D, 0, 4 * D);
  transpose_cvt<<<dim3(16, 64, 6), 256, 0, stream>>>(W2, W2T, 4 * D, D, 0, D);

  const dim3 g512(D / 128, NTOK / 128);          // (4, 32)
  const dim3 g2048(4 * D / 128, NTOK / 128);     // (16, 32)
  const int attn_grid = (NTOK / TSEQ) * NH * (TSEQ / 64);  // B*H*32 = 512
  for (int l = 0; l < NLAYER; ++l) {
    ln_kernel<<<NTOK / 4, 256, 0, stream>>>(x, ln1_g + l * D, ln1_b + l * D, h);
    gemm_bf16_kernel<false, false, false, false><<<g512, 256, 0, stream>>>(
        h, WqT + l * WDD, nullptr, nullptr, q, NTOK, D, D, D);
    gemm_bf16_kernel<false, false, false, false><<<g512, 256, 0, stream>>>(
        h, WkT + l * WDD, nullptr, nullptr, kbuf, NTOK, D, D, D);
    gemm_bf16_kernel<false, false, false, false><<<g512, 256, 0, stream>>>(
        h, WvT + l * WDD, nullptr, nullptr, vbuf, NTOK, D, D, D);
    attn_kernel<<<attn_grid, 256, 0, stream>>>(q, kbuf, vbuf, obuf);
    gemm_bf16_kernel<false, true, true, false><<<g512, 256, 0, stream>>>(
        obuf, WoT + l * WDD, bo + l * D, x, x, NTOK, D, D, D);
    ln_kernel<<<NTOK / 4, 256, 0, stream>>>(x, ln2_g + l * D, ln2_b + l * D, h);
    gemm_bf16_kernel<true, true, false, true><<<g2048, 256, 0, stream>>>(
        h, W1T + l * WD4, b1 + l * 4 * D, nullptr, mlp, NTOK, 4 * D, D, 4 * D);
    gemm_bf16_kernel<false, true, true, false><<<g512, 256, 0, stream>>>(
        mlp, W2T + l * WD4, b2 + l * D, x, x, NTOK, D, 4 * D, D);
  }
  ln_kernel<<<NTOK / 4, 256, 0, stream>>>(x, lnf_g, lnf_b, h);

  // head GEMM in N-chunks: transpose Whead[:, c0:c0+CN] -> ws (4.2 MB), then
  // bf16 GEMM into logits columns. CN multiple of 128.
  const int CHUNK = 4096;
  for (int c0 = 0; c0 < VOCAB; c0 += CHUNK) {
    const int CN = (VOCAB - c0 < CHUNK) ? (VOCAB - c0) : CHUNK;  // 4096 / 3328
    transpose_cvt<<<dim3(CN / 32, D / 32, 1), 256, 0, stream>>>(
        Whead, WTh, D, VOCAB, c0, CN);
    gemm_bf16_kernel<false, true, false, false>
        <<<dim3(CN / 128, NTOK / 128), 256, 0, stream>>>(
        h, WTh, bhead + c0, nullptr, out + c0, NTOK, CN, D, VOCAB);
  }
  loss_row_kernel<<<NTOK, 256, 0, stream>>>(out, targets, row_loss);
  loss_reduce_kernel<<<1, 256, 0, stream>>>(row_loss, out + (size_t)NTOK * VOCAB);
}